// Round 10
// baseline (305.771 us; speedup 1.0000x reference)
//
#include <hip/hip_runtime.h>
#include <math.h>

#define T_SEQ 2048
#define NH 16
#define HD 64
#define CEMB 1024
#define NEGINF -3.0e38f
#define RLN2 1.44269504f

typedef unsigned short ushort;
typedef unsigned int uint;
typedef __attribute__((ext_vector_type(8))) short short8;
typedef __attribute__((ext_vector_type(4))) float f32x4;

__device__ __forceinline__ float b2f(ushort h) {
    union { uint u; float f; } cv; cv.u = ((uint)h) << 16; return cv.f;
}
__device__ __forceinline__ ushort f2b(float f) {
    union { float f; uint u; } cv; cv.f = f;
    return (ushort)((cv.u + 0x7FFF + ((cv.u >> 16) & 1)) >> 16);
}
__device__ __forceinline__ ushort f2b_fast(float f) {   // round-half-up, 2 ops
    union { float f; uint u; } cv; cv.f = f;
    return (ushort)((cv.u + 0x8000) >> 16);
}
__device__ __forceinline__ void gl2lds16(const ushort* g, ushort* l) {
    __builtin_amdgcn_global_load_lds(
        (const __attribute__((address_space(1))) void*)g,
        (__attribute__((address_space(3))) void*)l, 16, 0, 0);
}

// ---------------------------------------------------------------------------
// merged f32 -> bf16 convert for x / Wqkv / Wproj PLUS Wlow precompute.
// blocks [0,8192): converts; blocks [8192,8224): Wlow rows 3072..3327.
// ---------------------------------------------------------------------------
__global__ __launch_bounds__(256) void convert_all_kernel(
    const float* __restrict__ x, const float* __restrict__ wqkv,
    const float* __restrict__ wproj, const float* __restrict__ W_recip,
    ushort* __restrict__ xb, ushort* __restrict__ wqkvb,
    ushort* __restrict__ wprojb)
{
    const int bid = blockIdx.x;
    if (bid < 8192) {
        const float* src; ushort* dst; int off;
        if (bid < 4096)      { src = x;     dst = xb;     off = bid; }
        else if (bid < 7168) { src = wqkv;  dst = wqkvb;  off = bid - 4096; }
        else                 { src = wproj; dst = wprojb; off = bid - 7168; }
        const int i = (off * 256 + threadIdx.x) * 4;
        const float4 v = *(const float4*)&src[i];
        ushort4 o;
        o.x = f2b(v.x); o.y = f2b(v.y); o.z = f2b(v.z); o.w = f2b(v.w);
        *(ushort4*)&dst[i] = o;
    } else {
        // Wlow[qk*128 + h*8 + r][e] = sum_d Wqkv[qk*1024+h*64+d][e] * W_recip[d][r]
        const int bw = bid - 8192;
        const int qk = bw >> 4, h = bw & 15;
        const int e0 = threadIdx.x * 4;
        f32x4 acc[8];
        #pragma unroll
        for (int r = 0; r < 8; ++r) acc[r] = (f32x4){0.f, 0.f, 0.f, 0.f};
        for (int d = 0; d < 64; ++d) {
            const float4 xv = *(const float4*)&wqkv[(size_t)(qk * 1024 + h * 64 + d) * 1024 + e0];
            #pragma unroll
            for (int r = 0; r < 8; ++r) {
                const float w = W_recip[d * 8 + r];
                acc[r][0] = fmaf(w, xv.x, acc[r][0]);
                acc[r][1] = fmaf(w, xv.y, acc[r][1]);
                acc[r][2] = fmaf(w, xv.z, acc[r][2]);
                acc[r][3] = fmaf(w, xv.w, acc[r][3]);
            }
        }
        #pragma unroll
        for (int r = 0; r < 8; ++r) {
            ushort4 o;
            o.x = f2b(acc[r][0]); o.y = f2b(acc[r][1]);
            o.z = f2b(acc[r][2]); o.w = f2b(acc[r][3]);
            *(ushort4*)&wqkvb[(size_t)(3072 + qk * 128 + h * 8 + r) * 1024 + e0] = o;
        }
    }
}

// ---------------------------------------------------------------------------
// bf16 MFMA GEMM core. smem carved: Asl = smem[0..4095], Bsl = smem[4096..].
// ---------------------------------------------------------------------------
#define GEMM_CORE(Aptr, Bptr, KDIM, SMEMSZ)                                    \
    __shared__ __align__(16) ushort smem[SMEMSZ];                              \
    ushort* Asl = smem;                                                        \
    ushort* Bsl = smem + 4096;                                                 \
    const int row0 = blockIdx.x * 128;                                         \
    const int col0 = blockIdx.y * 128;                                         \
    const int tid = threadIdx.x;                                               \
    const int wave = tid >> 6, lane = tid & 63;                                \
    const int wm = wave >> 1, wn = wave & 1;                                   \
    const int quad = lane >> 4, lq = lane & 15;                                \
    f32x4 acc[4][4];                                                           \
    _Pragma("unroll") for (int i = 0; i < 4; ++i)                              \
        _Pragma("unroll") for (int j = 0; j < 4; ++j)                          \
            acc[i][j] = (f32x4){0.f, 0.f, 0.f, 0.f};                           \
    for (int k0 = 0; k0 < (KDIM); k0 += 32) {                                  \
        _Pragma("unroll") for (int r2 = 0; r2 < 2; ++r2) {                     \
            const int c = r2 * 256 + tid;                                      \
            const int row = c >> 2, kc = (c & 3) * 8;                          \
            gl2lds16(&(Aptr)[(size_t)(row0 + row) * (KDIM) + k0 + kc], &Asl[c * 8]); \
            gl2lds16(&(Bptr)[(size_t)(col0 + row) * (KDIM) + k0 + kc], &Bsl[c * 8]); \
        }                                                                      \
        __syncthreads();                                                       \
        short8 af[4], bf[4];                                                   \
        _Pragma("unroll") for (int i = 0; i < 4; ++i)                          \
            af[i] = *(const short8*)&Asl[(wm * 64 + i * 16 + lq) * 32 + quad * 8]; \
        _Pragma("unroll") for (int j = 0; j < 4; ++j)                          \
            bf[j] = *(const short8*)&Bsl[(wn * 64 + j * 16 + lq) * 32 + quad * 8]; \
        _Pragma("unroll") for (int i = 0; i < 4; ++i)                          \
            _Pragma("unroll") for (int j = 0; j < 4; ++j)                      \
                acc[i][j] = __builtin_amdgcn_mfma_f32_16x16x32_bf16(           \
                    af[i], bf[j], acc[i][j], 0, 0, 0);                         \
        __syncthreads();                                                       \
    }

// Kernel 1: extended qkv GEMM, N=3328. Cs epilogue aliases Asl/Bsl.
// q side carries 0.125 * RLN2 (exp2 softmax) on both main and k_low tail.
__global__ __launch_bounds__(256) void gemm_qkv_kernel(
    const ushort* __restrict__ A, const ushort* __restrict__ Bt,
    const float* __restrict__ w_std, const float* __restrict__ w_rec,
    ushort* __restrict__ qh, ushort* __restrict__ kh, ushort* __restrict__ vt)
{
    GEMM_CORE(A, Bt, 1024, 17408)
    ushort* Cs = smem;   // 128*136 ushorts, aliases Asl/Bsl

    if (col0 >= 2048 && col0 < 3072) {
        // V region: vt[b][h][d][t], 4 consecutive t -> packed ushort4 store
        #pragma unroll
        for (int j = 0; j < 4; ++j) {
            const int cc = col0 + wn * 64 + j * 16 + lq;
            const int h = (cc >> 6) & 15;
            const int d = cc & 63;
            #pragma unroll
            for (int i = 0; i < 4; ++i) {
                const int rr0 = row0 + wm * 64 + i * 16 + quad * 4;
                const int b = rr0 >> 11, t0 = rr0 & 2047;
                ushort4 pv;
                pv.x = f2b(acc[i][j][0]); pv.y = f2b(acc[i][j][1]);
                pv.z = f2b(acc[i][j][2]); pv.w = f2b(acc[i][j][3]);
                *(ushort4*)&vt[((((size_t)b * NH + h) * HD + d) * T_SEQ + t0)] = pv;
            }
        }
    } else if (col0 < 2048) {
        // Q/K main: q scaled by w_std*0.125*RLN2, k unscaled; store d=0..55 only
        const bool isq = (col0 < 1024);
        #pragma unroll
        for (int j = 0; j < 4; ++j) {
            const int colc = wn * 64 + j * 16 + lq;
            const int h = ((col0 + colc) >> 6) & 15;
            const float sc = isq ? w_std[h] * (0.125f * RLN2) : 1.0f;
            #pragma unroll
            for (int i = 0; i < 4; ++i)
                #pragma unroll
                for (int r = 0; r < 4; ++r)
                    Cs[(wm * 64 + i * 16 + quad * 4 + r) * 136 + colc] =
                        f2b(acc[i][j][r] * sc);
        }
        __syncthreads();
        ushort* dst = isq ? qh : kh;
        const int hbase = (col0 >> 6) & 15;
        #pragma unroll
        for (int rep = 0; rep < 8; ++rep) {
            const int id = rep * 256 + tid;
            const int row = id >> 4, chunk = id & 15;
            if ((chunk & 7) == 7) continue;   // d=56..63 owned by tail blocks
            const int h = hbase + (chunk >> 3);
            const int d = (chunk & 7) * 8;
            const int rr = row0 + row;
            const int b = rr >> 11, t = rr & 2047;
            const uint4 val = *(const uint4*)&Cs[row * 136 + chunk * 8];
            *(uint4*)&dst[((((size_t)b * NH + h) * T_SEQ + t) * HD + d)] = val;
        }
    } else {
        // Tail: q_low -> kh tails (unscaled); k_low -> qh tails (w_rec*0.125*RLN2)
        const bool isqlow = (col0 < 3200);
        #pragma unroll
        for (int j = 0; j < 4; ++j) {
            const int colc = wn * 64 + j * 16 + lq;
            const int h = colc >> 3;
            const float sc = isqlow ? 1.0f : w_rec[h] * (0.125f * RLN2);
            #pragma unroll
            for (int i = 0; i < 4; ++i)
                #pragma unroll
                for (int r = 0; r < 4; ++r)
                    Cs[(wm * 64 + i * 16 + quad * 4 + r) * 136 + colc] =
                        f2b(acc[i][j][r] * sc);
        }
        __syncthreads();
        ushort* dst = isqlow ? kh : qh;
        #pragma unroll
        for (int rep = 0; rep < 8; ++rep) {
            const int id = rep * 256 + tid;
            const int row = id >> 4, h = id & 15;
            const int rr = row0 + row;
            const int b = rr >> 11, t = rr & 2047;
            const uint4 val = *(const uint4*)&Cs[row * 136 + h * 8];
            *(uint4*)&dst[((((size_t)b * NH + h) * T_SEQ + t) * HD + 56)] = val;
        }
    }
}

// Kernel 4: out(f32) = ao @ Wproj^T. Minimal smem -> high occupancy.
__global__ __launch_bounds__(256) void gemm_proj_kernel(
    const ushort* __restrict__ A, const ushort* __restrict__ Bt,
    float* __restrict__ C)
{
    GEMM_CORE(A, Bt, 1024, 8192)
    #pragma unroll
    for (int i = 0; i < 4; ++i) {
        #pragma unroll
        for (int r = 0; r < 4; ++r) {
            const int rr = row0 + wm * 64 + i * 16 + quad * 4 + r;
            #pragma unroll
            for (int j = 0; j < 4; ++j) {
                const int cc = col0 + wn * 64 + j * 16 + lq;
                C[(size_t)rr * 1024 + cc] = acc[i][j][r];
            }
        }
    }
}

// ---------------------------------------------------------------------------
// Kernel 3: MFMA attention, exp2 max-free softmax, direct LDS staging
// (round-7 style; round-8 register prefetch regressed and is reverted).
// Q staged through KPs then overwritten -> LDS 35.8 KB, 4 blocks/CU.
// ---------------------------------------------------------------------------
#define KSTR 72
#define VSTR 136
#define PSTR 136
__global__ __launch_bounds__(256, 4) void attn_kernel(
    const ushort* __restrict__ qa, const ushort* __restrict__ ka,
    const ushort* __restrict__ vt,
    const float* __restrict__ w_disc, const float* __restrict__ d_bias,
    ushort* __restrict__ out)
{
    __shared__ __align__(16) ushort KPs[128 * KSTR];  // Q stage -> Ks -> Ps
    __shared__ __align__(16) ushort Vs[64 * VSTR];
    const int bh = blockIdx.x;
    const int qt = 31 - blockIdx.y;      // longest blocks dispatched first
    const int h = bh & 15;
    const int b = bh >> 4;
    const int tid = threadIdx.x;
    const int wave = tid >> 6, lane = tid & 63;
    const int quad = lane >> 4, lq = lane & 15;
    const size_t base = (size_t)bh * T_SEQ * HD;
    const float wd = w_disc[h] * RLN2;   // exp2-domain bias weight

    // stage Q tile [m][d] through KPs, preload A-frags, then release buffer
    #pragma unroll
    for (int rep = 0; rep < 4; ++rep) {
        const int idx = rep * 256 + tid;
        const int m = idx >> 4, dq = (idx & 15) * 4;
        *(ushort4*)&KPs[m * KSTR + dq] =
            *(const ushort4*)&qa[base + (size_t)(qt * 64 + m) * 64 + dq];
    }
    __syncthreads();
    short8 aq[2];
    aq[0] = *(const short8*)&KPs[(wave * 16 + lq) * KSTR + quad * 8];
    aq[1] = *(const short8*)&KPs[(wave * 16 + lq) * KSTR + 32 + quad * 8];

    f32x4 o4[4];
    #pragma unroll
    for (int dt = 0; dt < 4; ++dt) o4[dt] = (f32x4){0.f, 0.f, 0.f, 0.f};
    float lsum[4] = {0.f, 0.f, 0.f, 0.f};
    const int qrow_base = qt * 64 + wave * 16 + quad * 4;
    const int nchunks = (qt + 2) >> 1;

    for (int c = 0; c < nchunks; ++c) {
        const int k0 = c * 128;
        __syncthreads();   // c=0: Q frag reads done; c>0: prior Ps/Vs reads done
        #pragma unroll
        for (int rep = 0; rep < 8; ++rep) {    // Ks: 128 keys x 64 d
            const int id = rep * 256 + tid;
            const int n = id >> 4, dq = (id & 15) * 4;
            *(ushort4*)&KPs[n * KSTR + dq] =
                *(const ushort4*)&ka[base + (size_t)(k0 + n) * 64 + dq];
        }
        #pragma unroll
        for (int rep = 0; rep < 8; ++rep) {    // Vs: 64 d x 128 keys
            const int id = rep * 256 + tid;
            const int d = id >> 5, kk = (id & 31) * 4;
            *(ushort4*)&Vs[d * VSTR + kk] =
                *(const ushort4*)&vt[base + (size_t)d * T_SEQ + k0 + kk];
        }
        __syncthreads();

        // S accumulators init with wd*bias (cols = keys), then QK^T
        f32x4 s4[8];
        #pragma unroll
        for (int nt = 0; nt < 8; ++nt) {
            const float bv = wd * d_bias[h * T_SEQ + k0 + nt * 16 + lq];
            s4[nt] = (f32x4){bv, bv, bv, bv};
        }
        #pragma unroll
        for (int ks = 0; ks < 2; ++ks)
            #pragma unroll
            for (int nt = 0; nt < 8; ++nt) {
                const short8 bk = *(const short8*)
                    &KPs[(nt * 16 + lq) * KSTR + ks * 32 + quad * 8];
                s4[nt] = __builtin_amdgcn_mfma_f32_16x16x32_bf16(
                    aq[ks], bk, s4[nt], 0, 0, 0);
            }
        __syncthreads();   // all waves done reading Ks -> Ps may overwrite

        const bool lastc = (c == nchunks - 1);
        #pragma unroll
        for (int r = 0; r < 4; ++r) {
            const int qrow = qrow_base + r;
            #pragma unroll
            for (int nt = 0; nt < 8; ++nt) {
                float s = s4[nt][r];
                if (lastc) {
                    const int key = k0 + nt * 16 + lq;
                    s = (key <= qrow) ? s : NEGINF;
                }
                const float p = exp2f(s);   // scores pre-scaled by 1/ln2
                lsum[r] += p;
                KPs[(wave * 16 + quad * 4 + r) * PSTR + nt * 16 + lq] = f2b_fast(p);
            }
        }
        // Ps rows are wave-private: no barrier before same-wave reads

        #pragma unroll
        for (int ks = 0; ks < 4; ++ks) {
            const short8 ap = *(const short8*)
                &KPs[(wave * 16 + lq) * PSTR + ks * 32 + quad * 8];
            #pragma unroll
            for (int dt = 0; dt < 4; ++dt) {
                const short8 bv = *(const short8*)
                    &Vs[(dt * 16 + lq) * VSTR + ks * 32 + quad * 8];
                o4[dt] = __builtin_amdgcn_mfma_f32_16x16x32_bf16(
                    ap, bv, o4[dt], 0, 0, 0);
            }
        }
    }

    // final row-sum reduction, normalize, store
    #pragma unroll
    for (int r = 0; r < 4; ++r) {
        float t = lsum[r];
        #pragma unroll
        for (int off = 8; off >= 1; off >>= 1)
            t += __shfl_xor(t, off, 64);
        lsum[r] = t;
    }
    #pragma unroll
    for (int r = 0; r < 4; ++r) {
        const float inv = 1.0f / lsum[r];
        const int t = qrow_base + r;
        const size_t obase = (((size_t)b * T_SEQ + t) * CEMB + h * HD);
        #pragma unroll
        for (int dt = 0; dt < 4; ++dt)
            out[obase + dt * 16 + lq] = f2b_fast(o4[dt][r] * inv);
    }
}

// ---------------------------------------------------------------------------
extern "C" void kernel_launch(void* const* d_in, const int* in_sizes, int n_in,
                              void* d_out, int out_size, void* d_ws, size_t ws_size,
                              hipStream_t stream) {
    const float* x       = (const float*)d_in[0];
    const float* Wqkv    = (const float*)d_in[1];
    const float* Wproj   = (const float*)d_in[2];
    const float* W_recip = (const float*)d_in[3];
    const float* w_std   = (const float*)d_in[4];
    const float* w_rec   = (const float*)d_in[5];
    const float* w_disc  = (const float*)d_in[6];
    const float* d_bias  = (const float*)d_in[7];
    float* out = (float*)d_out;

    const size_t NX = (size_t)4096 * 1024;
    const size_t NWQKVX = (size_t)3328 * 1024;
    const size_t NWPROJ = (size_t)1024 * 1024;
    ushort* xb     = (ushort*)d_ws;
    ushort* wqkvb  = xb + NX;
    ushort* wprojb = wqkvb + NWQKVX;
    ushort* qh     = wprojb + NWPROJ;
    ushort* kh     = qh + NX;
    ushort* vt     = kh + NX;
    ushort* ao     = vt + NX;

    convert_all_kernel<<<8224, 256, 0, stream>>>(x, Wqkv, Wproj, W_recip,
                                                 xb, wqkvb, wprojb);
    gemm_qkv_kernel<<<dim3(32, 26), 256, 0, stream>>>(xb, wqkvb, w_std, w_rec, qh, kh, vt);
    attn_kernel<<<dim3(32, 32), 256, 0, stream>>>(qh, kh, vt, w_disc, d_bias, ao);
    gemm_proj_kernel<<<dim3(32, 8), 256, 0, stream>>>(ao, wprojb, out);
}

// Round 11
// 231.781 us; speedup vs baseline: 1.3192x; 1.3192x over previous
//
#include <hip/hip_runtime.h>
#include <math.h>

#define T_SEQ 2048
#define NH 16
#define HD 64
#define CEMB 1024
#define NEGINF -3.0e38f
#define RLN2 1.44269504f

typedef unsigned short ushort;
typedef unsigned int uint;
typedef __attribute__((ext_vector_type(8))) short short8;
typedef __attribute__((ext_vector_type(4))) float f32x4;

__device__ __forceinline__ float b2f(ushort h) {
    union { uint u; float f; } cv; cv.u = ((uint)h) << 16; return cv.f;
}
__device__ __forceinline__ ushort f2b(float f) {
    union { float f; uint u; } cv; cv.f = f;
    return (ushort)((cv.u + 0x7FFF + ((cv.u >> 16) & 1)) >> 16);
}
__device__ __forceinline__ ushort f2b_fast(float f) {   // round-half-up, 2 ops
    union { float f; uint u; } cv; cv.f = f;
    return (ushort)((cv.u + 0x8000) >> 16);
}
__device__ __forceinline__ void gl2lds16(const ushort* g, ushort* l) {
    __builtin_amdgcn_global_load_lds(
        (const __attribute__((address_space(1))) void*)g,
        (__attribute__((address_space(3))) void*)l, 16, 0, 0);
}

// ---------------------------------------------------------------------------
// merged f32 -> bf16 convert for x / Wqkv / Wproj PLUS Wlow precompute.
// blocks [0,8192): converts; blocks [8192,8224): Wlow rows 3072..3327.
// ---------------------------------------------------------------------------
__global__ __launch_bounds__(256) void convert_all_kernel(
    const float* __restrict__ x, const float* __restrict__ wqkv,
    const float* __restrict__ wproj, const float* __restrict__ W_recip,
    ushort* __restrict__ xb, ushort* __restrict__ wqkvb,
    ushort* __restrict__ wprojb)
{
    const int bid = blockIdx.x;
    if (bid < 8192) {
        const float* src; ushort* dst; int off;
        if (bid < 4096)      { src = x;     dst = xb;     off = bid; }
        else if (bid < 7168) { src = wqkv;  dst = wqkvb;  off = bid - 4096; }
        else                 { src = wproj; dst = wprojb; off = bid - 7168; }
        const int i = (off * 256 + threadIdx.x) * 4;
        const float4 v = *(const float4*)&src[i];
        ushort4 o;
        o.x = f2b(v.x); o.y = f2b(v.y); o.z = f2b(v.z); o.w = f2b(v.w);
        *(ushort4*)&dst[i] = o;
    } else {
        // Wlow[qk*128 + h*8 + r][e] = sum_d Wqkv[qk*1024+h*64+d][e] * W_recip[d][r]
        const int bw = bid - 8192;
        const int qk = bw >> 4, h = bw & 15;
        const int e0 = threadIdx.x * 4;
        f32x4 acc[8];
        #pragma unroll
        for (int r = 0; r < 8; ++r) acc[r] = (f32x4){0.f, 0.f, 0.f, 0.f};
        for (int d = 0; d < 64; ++d) {
            const float4 xv = *(const float4*)&wqkv[(size_t)(qk * 1024 + h * 64 + d) * 1024 + e0];
            #pragma unroll
            for (int r = 0; r < 8; ++r) {
                const float w = W_recip[d * 8 + r];
                acc[r][0] = fmaf(w, xv.x, acc[r][0]);
                acc[r][1] = fmaf(w, xv.y, acc[r][1]);
                acc[r][2] = fmaf(w, xv.z, acc[r][2]);
                acc[r][3] = fmaf(w, xv.w, acc[r][3]);
            }
        }
        #pragma unroll
        for (int r = 0; r < 8; ++r) {
            ushort4 o;
            o.x = f2b(acc[r][0]); o.y = f2b(acc[r][1]);
            o.z = f2b(acc[r][2]); o.w = f2b(acc[r][3]);
            *(ushort4*)&wqkvb[(size_t)(3072 + qk * 128 + h * 8 + r) * 1024 + e0] = o;
        }
    }
}

// ---------------------------------------------------------------------------
// bf16 MFMA GEMM core. smem carved: Asl = smem[0..4095], Bsl = smem[4096..].
// ---------------------------------------------------------------------------
#define GEMM_CORE(Aptr, Bptr, KDIM, SMEMSZ)                                    \
    __shared__ __align__(16) ushort smem[SMEMSZ];                              \
    ushort* Asl = smem;                                                        \
    ushort* Bsl = smem + 4096;                                                 \
    const int row0 = blockIdx.x * 128;                                         \
    const int col0 = blockIdx.y * 128;                                         \
    const int tid = threadIdx.x;                                               \
    const int wave = tid >> 6, lane = tid & 63;                                \
    const int wm = wave >> 1, wn = wave & 1;                                   \
    const int quad = lane >> 4, lq = lane & 15;                                \
    f32x4 acc[4][4];                                                           \
    _Pragma("unroll") for (int i = 0; i < 4; ++i)                              \
        _Pragma("unroll") for (int j = 0; j < 4; ++j)                          \
            acc[i][j] = (f32x4){0.f, 0.f, 0.f, 0.f};                           \
    for (int k0 = 0; k0 < (KDIM); k0 += 32) {                                  \
        _Pragma("unroll") for (int r2 = 0; r2 < 2; ++r2) {                     \
            const int c = r2 * 256 + tid;                                      \
            const int row = c >> 2, kc = (c & 3) * 8;                          \
            gl2lds16(&(Aptr)[(size_t)(row0 + row) * (KDIM) + k0 + kc], &Asl[c * 8]); \
            gl2lds16(&(Bptr)[(size_t)(col0 + row) * (KDIM) + k0 + kc], &Bsl[c * 8]); \
        }                                                                      \
        __syncthreads();                                                       \
        short8 af[4], bf[4];                                                   \
        _Pragma("unroll") for (int i = 0; i < 4; ++i)                          \
            af[i] = *(const short8*)&Asl[(wm * 64 + i * 16 + lq) * 32 + quad * 8]; \
        _Pragma("unroll") for (int j = 0; j < 4; ++j)                          \
            bf[j] = *(const short8*)&Bsl[(wn * 64 + j * 16 + lq) * 32 + quad * 8]; \
        _Pragma("unroll") for (int i = 0; i < 4; ++i)                          \
            _Pragma("unroll") for (int j = 0; j < 4; ++j)                      \
                acc[i][j] = __builtin_amdgcn_mfma_f32_16x16x32_bf16(           \
                    af[i], bf[j], acc[i][j], 0, 0, 0);                         \
        __syncthreads();                                                       \
    }

// Kernel 1: extended qkv GEMM, N=3328. Cs epilogue aliases Asl/Bsl.
// q side carries 0.125 * RLN2 (exp2 softmax) on both main and k_low tail.
__global__ __launch_bounds__(256) void gemm_qkv_kernel(
    const ushort* __restrict__ A, const ushort* __restrict__ Bt,
    const float* __restrict__ w_std, const float* __restrict__ w_rec,
    ushort* __restrict__ qh, ushort* __restrict__ kh, ushort* __restrict__ vt)
{
    GEMM_CORE(A, Bt, 1024, 17408)
    ushort* Cs = smem;   // 128*136 ushorts, aliases Asl/Bsl

    if (col0 >= 2048 && col0 < 3072) {
        // V region: vt[b][h][d][t], 4 consecutive t -> packed ushort4 store
        #pragma unroll
        for (int j = 0; j < 4; ++j) {
            const int cc = col0 + wn * 64 + j * 16 + lq;
            const int h = (cc >> 6) & 15;
            const int d = cc & 63;
            #pragma unroll
            for (int i = 0; i < 4; ++i) {
                const int rr0 = row0 + wm * 64 + i * 16 + quad * 4;
                const int b = rr0 >> 11, t0 = rr0 & 2047;
                ushort4 pv;
                pv.x = f2b(acc[i][j][0]); pv.y = f2b(acc[i][j][1]);
                pv.z = f2b(acc[i][j][2]); pv.w = f2b(acc[i][j][3]);
                *(ushort4*)&vt[((((size_t)b * NH + h) * HD + d) * T_SEQ + t0)] = pv;
            }
        }
    } else if (col0 < 2048) {
        // Q/K main: q scaled by w_std*0.125*RLN2, k unscaled; store d=0..55 only
        const bool isq = (col0 < 1024);
        #pragma unroll
        for (int j = 0; j < 4; ++j) {
            const int colc = wn * 64 + j * 16 + lq;
            const int h = ((col0 + colc) >> 6) & 15;
            const float sc = isq ? w_std[h] * (0.125f * RLN2) : 1.0f;
            #pragma unroll
            for (int i = 0; i < 4; ++i)
                #pragma unroll
                for (int r = 0; r < 4; ++r)
                    Cs[(wm * 64 + i * 16 + quad * 4 + r) * 136 + colc] =
                        f2b(acc[i][j][r] * sc);
        }
        __syncthreads();
        ushort* dst = isq ? qh : kh;
        const int hbase = (col0 >> 6) & 15;
        #pragma unroll
        for (int rep = 0; rep < 8; ++rep) {
            const int id = rep * 256 + tid;
            const int row = id >> 4, chunk = id & 15;
            if ((chunk & 7) == 7) continue;   // d=56..63 owned by tail blocks
            const int h = hbase + (chunk >> 3);
            const int d = (chunk & 7) * 8;
            const int rr = row0 + row;
            const int b = rr >> 11, t = rr & 2047;
            const uint4 val = *(const uint4*)&Cs[row * 136 + chunk * 8];
            *(uint4*)&dst[((((size_t)b * NH + h) * T_SEQ + t) * HD + d)] = val;
        }
    } else {
        // Tail: q_low -> kh tails (unscaled); k_low -> qh tails (w_rec*0.125*RLN2)
        const bool isqlow = (col0 < 3200);
        #pragma unroll
        for (int j = 0; j < 4; ++j) {
            const int colc = wn * 64 + j * 16 + lq;
            const int h = colc >> 3;
            const float sc = isqlow ? 1.0f : w_rec[h] * (0.125f * RLN2);
            #pragma unroll
            for (int i = 0; i < 4; ++i)
                #pragma unroll
                for (int r = 0; r < 4; ++r)
                    Cs[(wm * 64 + i * 16 + quad * 4 + r) * 136 + colc] =
                        f2b(acc[i][j][r] * sc);
        }
        __syncthreads();
        ushort* dst = isqlow ? kh : qh;
        #pragma unroll
        for (int rep = 0; rep < 8; ++rep) {
            const int id = rep * 256 + tid;
            const int row = id >> 4, h = id & 15;
            const int rr = row0 + row;
            const int b = rr >> 11, t = rr & 2047;
            const uint4 val = *(const uint4*)&Cs[row * 136 + h * 8];
            *(uint4*)&dst[((((size_t)b * NH + h) * T_SEQ + t) * HD + 56)] = val;
        }
    }
}

// Kernel 4: out(f32) = ao @ Wproj^T. Minimal smem -> high occupancy.
__global__ __launch_bounds__(256) void gemm_proj_kernel(
    const ushort* __restrict__ A, const ushort* __restrict__ Bt,
    float* __restrict__ C)
{
    GEMM_CORE(A, Bt, 1024, 8192)
    #pragma unroll
    for (int i = 0; i < 4; ++i) {
        #pragma unroll
        for (int r = 0; r < 4; ++r) {
            const int rr = row0 + wm * 64 + i * 16 + quad * 4 + r;
            #pragma unroll
            for (int j = 0; j < 4; ++j) {
                const int cc = col0 + wn * 64 + j * 16 + lq;
                C[(size_t)rr * 1024 + cc] = acc[i][j][r];
            }
        }
    }
}

// ---------------------------------------------------------------------------
// Kernel 3: MFMA attention, exp2 max-free softmax, direct LDS staging.
// Q staged through KPs then overwritten -> LDS 35.8 KB.
// __launch_bounds__(256,3): (256,4) round-10 experiment capped VGPRs at 64 and
// spilled the S accumulators to scratch (WRITE_SIZE 8->21 MB, 2x slower).
// At ~84 VGPRs (<=128 class) HW can still co-schedule 4 blocks/CU via LDS.
// ---------------------------------------------------------------------------
#define KSTR 72
#define VSTR 136
#define PSTR 136
__global__ __launch_bounds__(256, 3) void attn_kernel(
    const ushort* __restrict__ qa, const ushort* __restrict__ ka,
    const ushort* __restrict__ vt,
    const float* __restrict__ w_disc, const float* __restrict__ d_bias,
    ushort* __restrict__ out)
{
    __shared__ __align__(16) ushort KPs[128 * KSTR];  // Q stage -> Ks -> Ps
    __shared__ __align__(16) ushort Vs[64 * VSTR];
    const int bh = blockIdx.x;
    const int qt = 31 - blockIdx.y;      // longest blocks dispatched first
    const int h = bh & 15;
    const int b = bh >> 4;
    const int tid = threadIdx.x;
    const int wave = tid >> 6, lane = tid & 63;
    const int quad = lane >> 4, lq = lane & 15;
    const size_t base = (size_t)bh * T_SEQ * HD;
    const float wd = w_disc[h] * RLN2;   // exp2-domain bias weight

    // stage Q tile [m][d] through KPs, preload A-frags, then release buffer
    #pragma unroll
    for (int rep = 0; rep < 4; ++rep) {
        const int idx = rep * 256 + tid;
        const int m = idx >> 4, dq = (idx & 15) * 4;
        *(ushort4*)&KPs[m * KSTR + dq] =
            *(const ushort4*)&qa[base + (size_t)(qt * 64 + m) * 64 + dq];
    }
    __syncthreads();
    short8 aq[2];
    aq[0] = *(const short8*)&KPs[(wave * 16 + lq) * KSTR + quad * 8];
    aq[1] = *(const short8*)&KPs[(wave * 16 + lq) * KSTR + 32 + quad * 8];

    f32x4 o4[4];
    #pragma unroll
    for (int dt = 0; dt < 4; ++dt) o4[dt] = (f32x4){0.f, 0.f, 0.f, 0.f};
    float lsum[4] = {0.f, 0.f, 0.f, 0.f};
    const int qrow_base = qt * 64 + wave * 16 + quad * 4;
    const int nchunks = (qt + 2) >> 1;

    for (int c = 0; c < nchunks; ++c) {
        const int k0 = c * 128;
        __syncthreads();   // c=0: Q frag reads done; c>0: prior Ps/Vs reads done
        #pragma unroll
        for (int rep = 0; rep < 8; ++rep) {    // Ks: 128 keys x 64 d
            const int id = rep * 256 + tid;
            const int n = id >> 4, dq = (id & 15) * 4;
            *(ushort4*)&KPs[n * KSTR + dq] =
                *(const ushort4*)&ka[base + (size_t)(k0 + n) * 64 + dq];
        }
        #pragma unroll
        for (int rep = 0; rep < 8; ++rep) {    // Vs: 64 d x 128 keys
            const int id = rep * 256 + tid;
            const int d = id >> 5, kk = (id & 31) * 4;
            *(ushort4*)&Vs[d * VSTR + kk] =
                *(const ushort4*)&vt[base + (size_t)d * T_SEQ + k0 + kk];
        }
        __syncthreads();

        // S accumulators init with wd*bias (cols = keys), then QK^T
        f32x4 s4[8];
        #pragma unroll
        for (int nt = 0; nt < 8; ++nt) {
            const float bv = wd * d_bias[h * T_SEQ + k0 + nt * 16 + lq];
            s4[nt] = (f32x4){bv, bv, bv, bv};
        }
        #pragma unroll
        for (int ks = 0; ks < 2; ++ks)
            #pragma unroll
            for (int nt = 0; nt < 8; ++nt) {
                const short8 bk = *(const short8*)
                    &KPs[(nt * 16 + lq) * KSTR + ks * 32 + quad * 8];
                s4[nt] = __builtin_amdgcn_mfma_f32_16x16x32_bf16(
                    aq[ks], bk, s4[nt], 0, 0, 0);
            }
        __syncthreads();   // all waves done reading Ks -> Ps may overwrite

        const bool lastc = (c == nchunks - 1);
        #pragma unroll
        for (int r = 0; r < 4; ++r) {
            const int qrow = qrow_base + r;
            #pragma unroll
            for (int nt = 0; nt < 8; ++nt) {
                float s = s4[nt][r];
                if (lastc) {
                    const int key = k0 + nt * 16 + lq;
                    s = (key <= qrow) ? s : NEGINF;
                }
                const float p = exp2f(s);   // scores pre-scaled by 1/ln2
                lsum[r] += p;
                KPs[(wave * 16 + quad * 4 + r) * PSTR + nt * 16 + lq] = f2b_fast(p);
            }
        }
        // Ps rows are wave-private: no barrier before same-wave reads

        #pragma unroll
        for (int ks = 0; ks < 4; ++ks) {
            const short8 ap = *(const short8*)
                &KPs[(wave * 16 + lq) * PSTR + ks * 32 + quad * 8];
            #pragma unroll
            for (int dt = 0; dt < 4; ++dt) {
                const short8 bv = *(const short8*)
                    &Vs[(dt * 16 + lq) * VSTR + ks * 32 + quad * 8];
                o4[dt] = __builtin_amdgcn_mfma_f32_16x16x32_bf16(
                    ap, bv, o4[dt], 0, 0, 0);
            }
        }
    }

    // final row-sum reduction, normalize, store
    #pragma unroll
    for (int r = 0; r < 4; ++r) {
        float t = lsum[r];
        #pragma unroll
        for (int off = 8; off >= 1; off >>= 1)
            t += __shfl_xor(t, off, 64);
        lsum[r] = t;
    }
    #pragma unroll
    for (int r = 0; r < 4; ++r) {
        const float inv = 1.0f / lsum[r];
        const int t = qrow_base + r;
        const size_t obase = (((size_t)b * T_SEQ + t) * CEMB + h * HD);
        #pragma unroll
        for (int dt = 0; dt < 4; ++dt)
            out[obase + dt * 16 + lq] = f2b_fast(o4[dt][r] * inv);
    }
}

// ---------------------------------------------------------------------------
extern "C" void kernel_launch(void* const* d_in, const int* in_sizes, int n_in,
                              void* d_out, int out_size, void* d_ws, size_t ws_size,
                              hipStream_t stream) {
    const float* x       = (const float*)d_in[0];
    const float* Wqkv    = (const float*)d_in[1];
    const float* Wproj   = (const float*)d_in[2];
    const float* W_recip = (const float*)d_in[3];
    const float* w_std   = (const float*)d_in[4];
    const float* w_rec   = (const float*)d_in[5];
    const float* w_disc  = (const float*)d_in[6];
    const float* d_bias  = (const float*)d_in[7];
    float* out = (float*)d_out;

    const size_t NX = (size_t)4096 * 1024;
    const size_t NWQKVX = (size_t)3328 * 1024;
    const size_t NWPROJ = (size_t)1024 * 1024;
    ushort* xb     = (ushort*)d_ws;
    ushort* wqkvb  = xb + NX;
    ushort* wprojb = wqkvb + NWQKVX;
    ushort* qh     = wprojb + NWPROJ;
    ushort* kh     = qh + NX;
    ushort* vt     = kh + NX;
    ushort* ao     = vt + NX;

    convert_all_kernel<<<8224, 256, 0, stream>>>(x, Wqkv, Wproj, W_recip,
                                                 xb, wqkvb, wprojb);
    gemm_qkv_kernel<<<dim3(32, 26), 256, 0, stream>>>(xb, wqkvb, w_std, w_rec, qh, kh, vt);
    attn_kernel<<<dim3(32, 32), 256, 0, stream>>>(qh, kh, vt, w_disc, d_bias, ao);
    gemm_proj_kernel<<<dim3(32, 8), 256, 0, stream>>>(ao, wprojb, out);
}